// Round 3
// baseline (414.164 us; speedup 1.0000x reference)
//
#include <hip/hip_runtime.h>

// ---------------------------------------------------------------------------
// AttentionPooling: out[b,o] = sum_p softmax_over_o(qk^T)[o,p] * vbar[b,p]
//   q = wq x + bq, k = wk x + bk   (GEMM M=64 K=512 N=4096 per batch)
//   vbar[p] = mean_n (wv x)[p,n] + bv  -> computed as a 4th MFMA accumulator
//             in single-pass bf16 (rounding error averages over N=4096).
// q/k use 3-pass bf16 hi/lo emulation (wh*xh + wl*xh + wh*xl) for fp32-class
// logits (verified R1: absmax 1.2e-4 vs 1.8e-3 threshold).
// R2: barrier-free K-loop. Each wave loads its MFMA B-fragments of x directly
// from global (B[k][n]: n=lane&15 -> one wave owns each x element; no LDS, no
// __syncthreads in the hot loop). W pre-converted once to bf16 hi/lo in ws.
// R3: rename NZERO -> ZERO_CNT (glibc macro collision in xopen_lim.h).
// ---------------------------------------------------------------------------

typedef __attribute__((ext_vector_type(8))) short short8;          // 8 bf16
typedef __attribute__((ext_vector_type(4))) float floatx4;

#define MFMA16(a, b, c) __builtin_amdgcn_mfma_f32_16x16x32_bf16((a), (b), (c), 0, 0, 0)

__device__ __forceinline__ unsigned short f2bf(float f) {
  unsigned int u = __float_as_uint(f);
  u = u + 0x7fffu + ((u >> 16) & 1u);   // RNE
  return (unsigned short)(u >> 16);
}
__device__ __forceinline__ float bf2f(unsigned short h) {
  return __uint_as_float(((unsigned int)h) << 16);
}

constexpr int CB = 32;        // batch
constexpr int CC = 512;       // channels
constexpr int CO = 64;        // C/8
constexpr int NN = 4096;      // H*W
constexpr int QROW = 72;      // logits-exchange row stride (64 + 8 pad), ushorts

// ws layout: logits fp32[32*64*64] | vsum fp32[32*64] | ws5 bf16[5][16][64][32]
// ws5 mats: 0=wq_hi 1=wq_lo 2=wk_hi 3=wk_lo 4=wv_hi ; slab = [chunk][o][c_local]
constexpr int ZERO_CNT = CB * CO * CO + CB * CO;   // 133120 floats
constexpr int WMAT  = 16 * 64 * 32;                // 32768 ushorts per matrix

__global__ __launch_bounds__(256) void zero_kernel(float* __restrict__ p, int n) {
  const int i = blockIdx.x * 256 + threadIdx.x;
  if (i < n) p[i] = 0.0f;
}

__global__ __launch_bounds__(256) void prep_w_kernel(
    const float* __restrict__ wq, const float* __restrict__ wk,
    const float* __restrict__ wv, unsigned short* __restrict__ ws5)
{
  const int gid = blockIdx.x * 256 + threadIdx.x;   // 0..16383
#pragma unroll
  for (int e = 0; e < 2; ++e) {
    const int idx = e * 16384 + gid;                // 0..32767
    const int o = idx >> 9, c = idx & 511;
    const int dst = ((c >> 5) * 64 + o) * 32 + (c & 31);
    const float q = wq[idx], k = wk[idx], v = wv[idx];
    const unsigned short qh = f2bf(q), kh = f2bf(k);
    ws5[dst]             = qh;
    ws5[dst + WMAT]      = f2bf(q - bf2f(qh));
    ws5[dst + 2 * WMAT]  = kh;
    ws5[dst + 3 * WMAT]  = f2bf(k - bf2f(kh));
    ws5[dst + 4 * WMAT]  = f2bf(v);
  }
}

__global__ __launch_bounds__(256, 2) void proj_kernel(
    const float* __restrict__ x, const unsigned short* __restrict__ ws5,
    const float* __restrict__ bq, const float* __restrict__ bk,
    float* __restrict__ logits, float* __restrict__ vsum)
{
  __shared__ __align__(16) unsigned short smem[4 * 64 * QROW];  // 36 KiB
  __shared__ float vps[4][64];

  const int t    = threadIdx.x;
  const int lane = t & 63;
  const int wave = t >> 6;
  const int quad = lane >> 4;
  const int l15  = lane & 15;
  const int b    = blockIdx.x >> 5;
  const int tile = blockIdx.x & 31;

  floatx4 accq[4][2], acck[4][2], accv[4][2];
#pragma unroll
  for (int mf = 0; mf < 4; ++mf)
#pragma unroll
    for (int nf = 0; nf < 2; ++nf) {
      accq[mf][nf] = (floatx4)0.0f;
      acck[mf][nf] = (floatx4)0.0f;
      accv[mf][nf] = (floatx4)0.0f;
    }

  // per-lane x pointer: row c = (chunk*32 + quad*8 + j), col n = tile*128 +
  // wave*32 + nf*16 + l15
  const float* xp = x + (size_t)b * CC * NN + (size_t)(quad * 8) * NN
                      + tile * 128 + wave * 32 + l15;

  auto load_x = [&](float xv[2][8], const float* p) {
#pragma unroll
    for (int j = 0; j < 8; ++j) {
      xv[0][j] = p[(size_t)j * NN];
      xv[1][j] = p[(size_t)j * NN + 16];
    }
  };

  auto compute = [&](const float xv[2][8], int ch) {
    short8 xh[2], xl[2];
#pragma unroll
    for (int nf = 0; nf < 2; ++nf)
#pragma unroll
      for (int j = 0; j < 8; ++j) {
        const unsigned short h = f2bf(xv[nf][j]);
        xh[nf][j] = (short)h;
        xl[nf][j] = (short)f2bf(xv[nf][j] - bf2f(h));
      }
    const unsigned short* wch = ws5 + ch * 2048 + l15 * 32 + quad * 8;
#pragma unroll
    for (int mf = 0; mf < 4; ++mf) {
      const unsigned short* wo = wch + mf * 512;
      const short8 aqh = *reinterpret_cast<const short8*>(wo);
      const short8 aql = *reinterpret_cast<const short8*>(wo + WMAT);
      const short8 akh = *reinterpret_cast<const short8*>(wo + 2 * WMAT);
      const short8 akl = *reinterpret_cast<const short8*>(wo + 3 * WMAT);
      const short8 avh = *reinterpret_cast<const short8*>(wo + 4 * WMAT);
#pragma unroll
      for (int nf = 0; nf < 2; ++nf) {
        accq[mf][nf] = MFMA16(aqh, xh[nf], accq[mf][nf]);
        accq[mf][nf] = MFMA16(aql, xh[nf], accq[mf][nf]);
        accq[mf][nf] = MFMA16(aqh, xl[nf], accq[mf][nf]);
        acck[mf][nf] = MFMA16(akh, xh[nf], acck[mf][nf]);
        acck[mf][nf] = MFMA16(akl, xh[nf], acck[mf][nf]);
        acck[mf][nf] = MFMA16(akh, xl[nf], acck[mf][nf]);
        accv[mf][nf] = MFMA16(avh, xh[nf], accv[mf][nf]);
      }
    }
  };

  // software-pipelined K-loop: prefetch next chunk's x while computing current
  float xv0[2][8], xv1[2][8];
  load_x(xv0, xp); xp += (size_t)32 * NN;
  for (int ch = 0; ch < 14; ch += 2) {
    load_x(xv1, xp); xp += (size_t)32 * NN;
    compute(xv0, ch);
    load_x(xv0, xp); xp += (size_t)32 * NN;
    compute(xv1, ch + 1);
  }
  load_x(xv1, xp);
  compute(xv0, 14);
  compute(xv1, 15);

  // ---- biases (C/D layout: row o = mf*16 + quad*4 + r, col n = l15) ----
#pragma unroll
  for (int mf = 0; mf < 4; ++mf)
#pragma unroll
    for (int r = 0; r < 4; ++r) {
      const int o = mf * 16 + quad * 4 + r;
      const float bqv = bq[o], bkv = bk[o];
#pragma unroll
      for (int nf = 0; nf < 2; ++nf) {
        accq[mf][nf][r] += bqv;
        acck[mf][nf][r] += bkv;
      }
    }

  // ---- logits partial: S = q k^T over this n-tile (hi/lo 3-pass via LDS) ----
  constexpr int QHI = 0, QLO = 4608, KHI = 9216, KLO = 13824;
  floatx4 accS[4];
#pragma unroll
  for (int mf = 0; mf < 4; ++mf) accS[mf] = (floatx4)0.0f;

  for (int hh = 0; hh < 2; ++hh) {
    __syncthreads();
    if ((wave >> 1) == hh) {
      const int nbase = (wave & 1) * 32;
#pragma unroll
      for (int mf = 0; mf < 4; ++mf)
#pragma unroll
        for (int nf = 0; nf < 2; ++nf)
#pragma unroll
          for (int r = 0; r < 4; ++r) {
            const int o  = mf * 16 + quad * 4 + r;
            const int nc = nbase + nf * 16 + l15;
            const float qv = accq[mf][nf][r];
            const float kv = acck[mf][nf][r];
            const unsigned short qh = f2bf(qv);
            const unsigned short kh = f2bf(kv);
            smem[QHI + o * QROW + nc] = qh;
            smem[QLO + o * QROW + nc] = f2bf(qv - bf2f(qh));
            smem[KHI + o * QROW + nc] = kh;
            smem[KLO + o * QROW + nc] = f2bf(kv - bf2f(kh));
          }
    }
    __syncthreads();
#pragma unroll
    for (int ks = 0; ks < 2; ++ks) {
      const short8 bh = *reinterpret_cast<const short8*>(
          &smem[KHI + (wave * 16 + l15) * QROW + ks * 32 + quad * 8]);
      const short8 bl = *reinterpret_cast<const short8*>(
          &smem[KLO + (wave * 16 + l15) * QROW + ks * 32 + quad * 8]);
#pragma unroll
      for (int mf = 0; mf < 4; ++mf) {
        const short8 ah = *reinterpret_cast<const short8*>(
            &smem[QHI + (mf * 16 + l15) * QROW + ks * 32 + quad * 8]);
        const short8 al = *reinterpret_cast<const short8*>(
            &smem[QLO + (mf * 16 + l15) * QROW + ks * 32 + quad * 8]);
        accS[mf] = MFMA16(ah, bh, accS[mf]);
        accS[mf] = MFMA16(al, bh, accS[mf]);
        accS[mf] = MFMA16(ah, bl, accS[mf]);
      }
    }
  }

#pragma unroll
  for (int mf = 0; mf < 4; ++mf)
#pragma unroll
    for (int r = 0; r < 4; ++r) {
      const int o = mf * 16 + quad * 4 + r;
      const int p = wave * 16 + l15;
      atomicAdd(&logits[((size_t)b * CO + o) * CO + p], accS[mf][r]);
    }

  // ---- v reduction over n: vsum[b,p] += sum over this tile's 128 n ----
#pragma unroll
  for (int mf = 0; mf < 4; ++mf)
#pragma unroll
    for (int r = 0; r < 4; ++r) {
      float sv = accv[mf][0][r] + accv[mf][1][r];
      sv += __shfl_xor(sv, 1); sv += __shfl_xor(sv, 2);
      sv += __shfl_xor(sv, 4); sv += __shfl_xor(sv, 8);
      if (l15 == 0) vps[wave][mf * 16 + quad * 4 + r] = sv;
    }
  __syncthreads();
  if (t < CO) {
    const float s = vps[0][t] + vps[1][t] + vps[2][t] + vps[3][t];
    atomicAdd(&vsum[b * CO + t], s);
  }
}

__global__ __launch_bounds__(256) void finalize_kernel(
    const float* __restrict__ bv, const float* __restrict__ logits,
    const float* __restrict__ vsum, float* __restrict__ out)
{
  __shared__ float ls[CO * 65];
  __shared__ float w2_s[CO], cmax_s[CO];
  const int t = threadIdx.x;
  const int b = blockIdx.x;

#pragma unroll
  for (int i = 0; i < 16; ++i) {
    const int idx = t + i * 256;          // 0..4095
    ls[(idx >> 6) * 65 + (idx & 63)] = logits[(size_t)b * CO * CO + idx];
  }
  __syncthreads();

  if (t < CO) {  // column stats for p=t: softmax over rows o
    float m = -1e30f;
    for (int o = 0; o < CO; ++o) m = fmaxf(m, ls[o * 65 + t]);
    float sum = 0.f;
    for (int o = 0; o < CO; ++o) sum += __expf(ls[o * 65 + t] - m);
    cmax_s[t] = m;
    const float vbar = vsum[b * CO + t] * (1.0f / 4096.0f) + bv[t];
    w2_s[t] = vbar / sum;
  }
  __syncthreads();

  if (t < CO) {
    float acc = 0.f;
    for (int p = 0; p < CO; ++p)
      acc += __expf(ls[t * 65 + p] - cmax_s[p]) * w2_s[p];
    out[b * CO + t] = acc;
  }
}

extern "C" void kernel_launch(void* const* d_in, const int* in_sizes, int n_in,
                              void* d_out, int out_size, void* d_ws, size_t ws_size,
                              hipStream_t stream) {
  const float* x  = (const float*)d_in[0];
  const float* wq = (const float*)d_in[1];
  const float* bq = (const float*)d_in[2];
  const float* wk = (const float*)d_in[3];
  const float* bk = (const float*)d_in[4];
  const float* wv = (const float*)d_in[5];
  const float* bv = (const float*)d_in[6];
  float* out = (float*)d_out;

  float* logits = (float*)d_ws;                       // 131072 floats
  float* vsum   = logits + CB * CO * CO;              // 2048 floats
  unsigned short* ws5 = (unsigned short*)(vsum + CB * CO);  // 5*32768 ushorts

  zero_kernel<<<(ZERO_CNT + 255) / 256, 256, 0, stream>>>(logits, ZERO_CNT);
  prep_w_kernel<<<64, 256, 0, stream>>>(wq, wk, wv, ws5);
  proj_kernel<<<CB * 32, 256, 0, stream>>>(x, ws5, bq, bk, logits, vsum);
  finalize_kernel<<<CB, 256, 0, stream>>>(bv, logits, vsum, out);
}